// Round 1
// baseline (106.247 us; speedup 1.0000x reference)
//
#include <hip/hip_runtime.h>
#include <hip/hip_bf16.h>

// Problem constants (from reference): B=128, C=21, L=2048, W=32, S=8, O=16
// M=251, NW=252, NK=4032, K=C*W=672
#define Bb   128
#define Cc   21
#define Ll   2048
#define Ww   32
#define Ss   8
#define Oo   16
#define NWw  252
#define NKk  4032
#define Kk   672
#define KP   680   // LDS pitch in bf16 elems: 85 x 16B granules, odd -> conflict-free b128
#define BT   64    // batch tile

typedef __attribute__((ext_vector_type(8))) short  short8;  // 8 bf16 = 4 VGPRs
typedef __attribute__((ext_vector_type(4))) float  f32x4;

static __device__ __forceinline__ unsigned short f2bf(float f) {
    union { __hip_bfloat16 h; unsigned short u; } cv;
    cv.h = __float2bfloat16(f);
    return cv.u;
}

// One block per window j. 256 threads = 4 waves.
// LDS: ws 16x680 bf16 (21.8 KB) + xs 64x680 bf16 (87 KB) = 108.8 KB -> 1 block/CU.
__global__ __launch_bounds__(256, 1)
void fb_fwd(const float* __restrict__ x, const float* __restrict__ w,
            float* __restrict__ out) {
    __shared__ unsigned short ws[Oo * KP];
    __shared__ unsigned short xs[BT * KP];

    const int j    = blockIdx.x;
    const int s    = (j < NWw - 1) ? j * Ss : (Ll - Ww);  // STARTS[j]
    const int tid  = threadIdx.x;
    const int lane = tid & 63;
    const int wv   = tid >> 6;       // wave id 0..3
    const int col  = lane & 15;      // MFMA n (=o) / m row selector
    const int quad = lane >> 4;      // k-chunk selector

    // ---- stage weight[j]: 16 x 672 fp32 -> bf16 LDS, [o][k] layout (B^T) ----
    {
        const float4* wj4 = (const float4*)(w + (size_t)j * Oo * Kk);
        for (int t = tid; t < Oo * (Kk / 4); t += 256) {   // 2688 float4
            float4 v = wj4[t];                              // rows contiguous
            int o = t / (Kk / 4);                           // Kk/4 = 168
            int r = t - o * (Kk / 4);
            ushort4 p = make_ushort4(f2bf(v.x), f2bf(v.y), f2bf(v.z), f2bf(v.w));
            *(ushort4*)&ws[o * KP + r * 4] = p;
        }
    }

    for (int bb = 0; bb < Bb; bb += BT) {
        // ---- stage x patch: BT x (21 c-rows x 32 cols) fp32 -> bf16 ----
        // k = c*32 + wcol matches weight's c*W + w ordering.
        for (int t = tid; t < BT * Cc * 8; t += 256) {      // 10752 float4
            int rc = t >> 3;            // 0..1343  (b,c) row-chunk
            int q  = t & 7;             // float4 within 32-col chunk
            int b  = rc / Cc;
            int c  = rc - b * Cc;
            // s multiple of 8 -> s+q*4 multiple of 4 elems -> 16B aligned
            const float4 v = *(const float4*)(x + ((size_t)(bb + b) * Cc + c) * Ll + s + q * 4);
            ushort4 p = make_ushort4(f2bf(v.x), f2bf(v.y), f2bf(v.z), f2bf(v.w));
            *(ushort4*)&xs[b * KP + c * 32 + q * 4] = p;
        }
        __syncthreads();

        // ---- MFMA: wave wv -> batch rows [bb + wv*16, +16), all 16 o ----
        // A[m=lane&15][k=quad*8+jj], B[k=quad*8+jj][n=lane&15] (weight row n)
        f32x4 acc = {0.f, 0.f, 0.f, 0.f};
        const unsigned short* xrow = &xs[(wv * 16 + col) * KP + quad * 8];
        const unsigned short* wrow = &ws[col * KP + quad * 8];
#pragma unroll
        for (int kc = 0; kc < Cc; ++kc) {                   // 21 k-steps of 32
            short8 a  = *(const short8*)(xrow + kc * 32);
            short8 bf = *(const short8*)(wrow + kc * 32);
            acc = __builtin_amdgcn_mfma_f32_16x16x32_bf16(a, bf, acc, 0, 0, 0);
        }

        // ---- C/D layout: col = lane&15, row = quad*4 + reg ----
        const int rbase = bb + wv * 16 + quad * 4;
        float* op = out + (size_t)rbase * NKk + j * 16 + col;
#pragma unroll
        for (int r = 0; r < 4; ++r)
            op[(size_t)r * NKk] = acc[r];

        __syncthreads();  // protect xs before next tile's staging
    }
}

extern "C" void kernel_launch(void* const* d_in, const int* in_sizes, int n_in,
                              void* d_out, int out_size, void* d_ws, size_t ws_size,
                              hipStream_t stream) {
    const float* x = (const float*)d_in[0];   // (128, 21, 2048) fp32
    const float* w = (const float*)d_in[1];   // (4032, 672) fp32
    float* out = (float*)d_out;               // (128, 4032) fp32
    fb_fwd<<<dim3(NWw), dim3(256), 0, stream>>>(x, w, out);
}

// Round 2
// 93.479 us; speedup vs baseline: 1.1366x; 1.1366x over previous
//
#include <hip/hip_runtime.h>
#include <hip/hip_bf16.h>

// Problem constants: B=128, C=21, L=2048, W=32, S=8, O=16, NW=252, NK=4032, K=672
#define Bb   128
#define Cc   21
#define Ll   2048
#define Ss   8
#define Oo   16
#define NWw  252
#define NKk  4032
#define Kk   672
#define KP   680   // LDS pitch (bf16): 85 x 16B granules, odd -> conflict-light b128

typedef __attribute__((ext_vector_type(8))) short  short8;  // 8 bf16 = 4 VGPRs
typedef __attribute__((ext_vector_type(4))) float  f32x4;

static __device__ __forceinline__ unsigned short f2bf(float f) {
    union { __hip_bfloat16 h; unsigned short u; } cv;
    cv.h = __float2bfloat16(f);
    return cv.u;
}

// One block per window j. 512 threads = 8 waves; wave wv owns batch rows
// [wv*16, wv*16+16) — all 128 batches in one block, weight read once.
// LDS holds ONLY the bf16 weight tile (21.8 KB): x has zero intra-block reuse,
// so A-fragments are loaded straight from global (32 B/lane, 16B-aligned) and
// converted fp32->bf16 in-register. One barrier per block.
__global__ __launch_bounds__(512)
void fb_fwd(const float* __restrict__ x, const float* __restrict__ w,
            float* __restrict__ out) {
    __shared__ unsigned short ws[Oo * KP];

    const int j    = blockIdx.x;
    const int s    = (j < NWw - 1) ? j * Ss : (Ll - 32);  // STARTS[j], mult of 8
    const int tid  = threadIdx.x;
    const int lane = tid & 63;
    const int wv   = tid >> 6;       // 0..7: m-tile id
    const int col  = lane & 15;      // MFMA row (A m) / col (B n)
    const int quad = lane >> 4;      // k-chunk selector

    // ---- stage weight[j]: 16 x 672 fp32 -> bf16 LDS, [o][k] (B^T) ----
    {
        const float4* wj4 = (const float4*)(w + (size_t)j * Oo * Kk);
        for (int t = tid; t < Oo * (Kk / 4); t += 512) {   // 2688 float4
            float4 v = wj4[t];
            int o = t / (Kk / 4);                           // Kk/4 = 168
            int r = t - o * (Kk / 4);
            ushort4 p = make_ushort4(f2bf(v.x), f2bf(v.y), f2bf(v.z), f2bf(v.w));
            *(ushort4*)&ws[o * KP + r * 4] = p;
        }
    }
    __syncthreads();

    // A fragment source: row (wv*16+col), k = c*32 + quad*8 .. +8
    const float* xrow = x + ((size_t)(wv * 16 + col) * Cc) * Ll + s + quad * 8;
    const unsigned short* wrow = &ws[col * KP + quad * 8];

    f32x4 acc = {0.f, 0.f, 0.f, 0.f};
#pragma unroll
    for (int c = 0; c < Cc; ++c) {                 // 21 k-steps of 32
        const float4 a0 = *(const float4*)(xrow + (size_t)c * Ll);
        const float4 a1 = *(const float4*)(xrow + (size_t)c * Ll + 4);
        short8 a;
        a[0] = (short)f2bf(a0.x); a[1] = (short)f2bf(a0.y);
        a[2] = (short)f2bf(a0.z); a[3] = (short)f2bf(a0.w);
        a[4] = (short)f2bf(a1.x); a[5] = (short)f2bf(a1.y);
        a[6] = (short)f2bf(a1.z); a[7] = (short)f2bf(a1.w);
        const short8 bfr = *(const short8*)(wrow + c * 32);
        acc = __builtin_amdgcn_mfma_f32_16x16x32_bf16(a, bfr, acc, 0, 0, 0);
    }

    // ---- C/D layout: col = lane&15, row = quad*4 + reg ----
    const int rbase = wv * 16 + quad * 4;
    float* op = out + (size_t)rbase * NKk + j * 16 + col;
#pragma unroll
    for (int r = 0; r < 4; ++r)
        op[(size_t)r * NKk] = acc[r];
}

extern "C" void kernel_launch(void* const* d_in, const int* in_sizes, int n_in,
                              void* d_out, int out_size, void* d_ws, size_t ws_size,
                              hipStream_t stream) {
    const float* x = (const float*)d_in[0];   // (128, 21, 2048) fp32
    const float* w = (const float*)d_in[1];   // (4032, 672) fp32
    float* out = (float*)d_out;               // (128, 4032) fp32
    fb_fwd<<<dim3(NWw), dim3(512), 0, stream>>>(x, w, out);
}